// Round 1
// baseline (469.463 us; speedup 1.0000x reference)
//
#include <hip/hip_runtime.h>
#include <math.h>

#define NROWS 131072   // 32*64*64
#define CDIM  64
#define NCODE 1024

__global__ void vq_zero_loss(float* loss) { *loss = 0.0f; }

__global__ __launch_bounds__(256) void vq_main(
    const float* __restrict__ ze, const float* __restrict__ embs,
    float* __restrict__ out, float* __restrict__ loss)
{
    __shared__ float s_e2[NCODE];
    __shared__ float s_red[4];
    const int tid = threadIdx.x;

    // --- codebook squared norms -> LDS (each block computes its own copy) ---
    #pragma unroll
    for (int j = 0; j < 4; ++j) {
        const int k = tid + 256 * j;
        const float* ep = embs + (size_t)k * CDIM;
        float s = 0.0f;
        #pragma unroll
        for (int d = 0; d < CDIM; d += 4) {
            const float4 e4 = *(const float4*)(ep + d);
            s = fmaf(e4.x, e4.x, s);
            s = fmaf(e4.y, e4.y, s);
            s = fmaf(e4.z, e4.z, s);
            s = fmaf(e4.w, e4.w, s);
        }
        s_e2[k] = s;
    }
    __syncthreads();

    // --- load this thread's row into registers ---
    const int row = blockIdx.x * 256 + tid;
    const float* zp = ze + (size_t)row * CDIM;
    float z[CDIM];
    #pragma unroll
    for (int d = 0; d < CDIM; d += 4) {
        const float4 v = *(const float4*)(zp + d);
        z[d + 0] = v.x; z[d + 1] = v.y; z[d + 2] = v.z; z[d + 3] = v.w;
    }

    // --- argmin over codebook: dist = ||e||^2 - 2 z.e  (||z||^2 dropped) ---
    float best = INFINITY;
    int bidx = 0;
    for (int k = 0; k < NCODE; ++k) {
        const float* __restrict__ ep = embs + (size_t)k * CDIM;  // wave-uniform -> s_load
        float a0 = 0.0f, a1 = 0.0f, a2 = 0.0f, a3 = 0.0f;
        #pragma unroll
        for (int d = 0; d < CDIM; d += 4) {
            a0 = fmaf(z[d + 0], ep[d + 0], a0);
            a1 = fmaf(z[d + 1], ep[d + 1], a1);
            a2 = fmaf(z[d + 2], ep[d + 2], a2);
            a3 = fmaf(z[d + 3], ep[d + 3], a3);
        }
        const float dist = s_e2[k] - 2.0f * ((a0 + a1) + (a2 + a3));
        if (dist < best) { best = dist; bidx = k; }   // strict < : first-min tie-break
    }

    // --- gather winner, write zq, accumulate (zq - ze)^2 ---
    const float* ep = embs + (size_t)bidx * CDIM;
    float* op = out + (size_t)row * CDIM;
    float psum = 0.0f;
    #pragma unroll
    for (int d = 0; d < CDIM; d += 4) {
        const float4 e4 = *(const float4*)(ep + d);
        *(float4*)(op + d) = e4;
        const float d0 = e4.x - z[d + 0];
        const float d1 = e4.y - z[d + 1];
        const float d2 = e4.z - z[d + 2];
        const float d3 = e4.w - z[d + 3];
        psum = fmaf(d0, d0, psum);
        psum = fmaf(d1, d1, psum);
        psum = fmaf(d2, d2, psum);
        psum = fmaf(d3, d3, psum);
    }

    // --- loss reduction: wave shuffle -> LDS -> one atomic per block ---
    #pragma unroll
    for (int off = 32; off > 0; off >>= 1)
        psum += __shfl_down(psum, off, 64);
    const int wave = tid >> 6;
    if ((tid & 63) == 0) s_red[wave] = psum;
    __syncthreads();
    if (tid == 0) {
        const float b = (s_red[0] + s_red[1]) + (s_red[2] + s_red[3]);
        // loss = 1.25 * sum / (NROWS*CDIM), pre-scaled per block
        atomicAdd(loss, b * (1.25f / ((float)NROWS * (float)CDIM)));
    }
}

extern "C" void kernel_launch(void* const* d_in, const int* in_sizes, int n_in,
                              void* d_out, int out_size, void* d_ws, size_t ws_size,
                              hipStream_t stream) {
    const float* ze   = (const float*)d_in[0];   // [32,64,64,64] fp32
    const float* embs = (const float*)d_in[1];   // [1024,64] fp32
    float* out  = (float*)d_out;                 // zq_st (8388608) then loss (1)
    float* loss = out + (out_size - 1);

    vq_zero_loss<<<1, 1, 0, stream>>>(loss);
    vq_main<<<NROWS / 256, 256, 0, stream>>>(ze, embs, out, loss);
}